// Round 8
// baseline (269.150 us; speedup 1.0000x reference)
//
#include <hip/hip_runtime.h>
#include <hip/hip_fp16.h>

// GCN encoder on MI355X. CSR (counting sort by dst) + fused gather aggregation.
// fp16 activations; 4-byte edge records {w:fp16 | src:u16} (N=50000 < 2^16);
// scalar (wave-uniform) record loads; gathers restructured as edge-subgroup x
// channel-lane with 8-byte row loads: gather1 = 2 subs x 32 ch-lanes, gather2 =
// 4 subs x 16 ch-lanes -> 16 edges in flight per iteration, fewer vmem
// instructions per edge. MFMA layer-1 GEMM; LN/ReLU/W2/L2 epilogues fused.

#define K_DIM 128

typedef _Float16 f16x8 __attribute__((ext_vector_type(8)));
typedef _Float16 f16x4 __attribute__((ext_vector_type(4)));
typedef float f32x4 __attribute__((ext_vector_type(4)));

__device__ __forceinline__ float2 h2f(unsigned int u) {
    __half2 h = __builtin_bit_cast(__half2, u);
    return __half22float2(h);
}
__device__ __forceinline__ float wbits(unsigned int r) {
    return __half2float(__ushort_as_half((unsigned short)(r >> 16)));
}

// ---------- CSR build ----------
__global__ __launch_bounds__(256) void hist_kernel(const int* __restrict__ dst,
                                                   int* counts, int E) {
    int i = blockIdx.x * 256 + threadIdx.x;
    if (i < E) atomicAdd(&counts[dst[i]], 1);
}

__global__ __launch_bounds__(256) void scan_block_kernel(const int* __restrict__ counts,
                                                         int* row_ptr, int* partials,
                                                         float* dinv, int N) {
    __shared__ int sm[256];
    int t = threadIdx.x;
    int i = blockIdx.x * 256 + t;
    int v = (i < N) ? counts[i] : 0;
    if (i < N) dinv[i] = rsqrtf((float)(v + 1));
    sm[t] = v;
    __syncthreads();
    for (int off = 1; off < 256; off <<= 1) {
        int add = (t >= off) ? sm[t - off] : 0;
        __syncthreads();
        sm[t] += add;
        __syncthreads();
    }
    if (i < N) row_ptr[i] = sm[t] - v;  // block-local exclusive
    if (t == 255) partials[blockIdx.x] = sm[255];
}

__global__ __launch_bounds__(256) void scan_partials_kernel(int* partials, int NB) {
    __shared__ int sm[256];
    int t = threadIdx.x;
    int v = (t < NB) ? partials[t] : 0;
    sm[t] = v;
    __syncthreads();
    for (int off = 1; off < 256; off <<= 1) {
        int add = (t >= off) ? sm[t - off] : 0;
        __syncthreads();
        sm[t] += add;
        __syncthreads();
    }
    if (t < NB) partials[t] = sm[t] - v;  // exclusive
}

// fill: row_ptr[d] is a block-local cursor; global pos = cursor + partials[d>>8].
__global__ __launch_bounds__(256) void fill_kernel(const int* __restrict__ src,
                                                   const int* __restrict__ dst,
                                                   const float* __restrict__ dinv,
                                                   int* row_ptr,
                                                   const int* __restrict__ partials,
                                                   unsigned int* edges, int E) {
    int i = blockIdx.x * 256 + threadIdx.x;
    if (i < E) {
        int d = dst[i];
        int s = src[i];
        int pos = atomicAdd(&row_ptr[d], 1) + partials[d >> 8];
        float w = dinv[s] * dinv[d];
        unsigned int rec = ((unsigned int)__half_as_ushort(__float2half_rn(w)) << 16)
                         | (unsigned int)s;
        edges[pos] = rec;
    }
}

// ---------- W1 -> W1^T fp16 ----------
__global__ __launch_bounds__(256) void wt_prep_kernel(const float* __restrict__ W1,
                                                      _Float16* __restrict__ WT) {
    int idx = blockIdx.x * 256 + threadIdx.x;
    if (idx < 128 * 128) {
        int k = idx >> 7, j = idx & 127;
        WT[j * 128 + k] = (_Float16)W1[idx];
    }
}

// ---------- GEMM1 (MFMA): h1 = X @ W1, f16 out ----------
__global__ __launch_bounds__(256) void gemm1_mfma_kernel(const float* __restrict__ X,
                                                         const _Float16* __restrict__ WT,
                                                         __half* __restrict__ H, int N) {
    __shared__ _Float16 As[64][136];

    int row0 = blockIdx.x * 64;
    {
        int r = threadIdx.x >> 2;
        int c0 = (threadIdx.x & 3) * 32;
        int row = row0 + r;
        if (row < N) {
            const float4* srcp = (const float4*)(X + (size_t)row * 128 + c0);
#pragma unroll
            for (int i = 0; i < 8; ++i) {
                float4 v = srcp[i];
                f16x4 h = {(_Float16)v.x, (_Float16)v.y, (_Float16)v.z, (_Float16)v.w};
                *(f16x4*)&As[r][c0 + 4 * i] = h;
            }
        } else {
            f16x4 z = {};
#pragma unroll
            for (int i = 0; i < 8; ++i) *(f16x4*)&As[r][c0 + 4 * i] = z;
        }
    }
    __syncthreads();

    int wave = threadIdx.x >> 6;
    int lane = threadIdx.x & 63;
    int l15 = lane & 15;
    int k0 = (lane >> 4) * 8;
    int arow = wave * 16 + l15;

    f32x4 acc[8] = {};
#pragma unroll
    for (int ks = 0; ks < 4; ++ks) {
        f16x8 a = *(const f16x8*)&As[arow][ks * 32 + k0];
#pragma unroll
        for (int t = 0; t < 8; ++t) {
            f16x8 b = *(const f16x8*)(WT + (size_t)(t * 16 + l15) * 128 + ks * 32 + k0);
            acc[t] = __builtin_amdgcn_mfma_f32_16x16x32_f16(a, b, acc[t], 0, 0, 0);
        }
    }

    int rbase = row0 + wave * 16 + (lane >> 4) * 4;
#pragma unroll
    for (int t = 0; t < 8; ++t) {
#pragma unroll
        for (int r = 0; r < 4; ++r) {
            int row = rbase + r;
            if (row < N) H[(size_t)row * 128 + t * 16 + l15] = __float2half(acc[t][r]);
        }
    }
}

// ---------- gather1 fused: agg(h1) -> +b1 -> LN -> ReLU -> @W2 -> h3 (fp16) ----------
// Wave = one node. lane = sub(2) x ch(32); lane loads uint2 (4 halves) of its
// sub's edge row; 16 edges per iteration. Channels duplicated 2x across subs
// after the xor-32 combine (LN reductions use /256).
__global__ __launch_bounds__(256) void gather1_fused_kernel(
    const __half* __restrict__ h1, const float* __restrict__ dinv,
    const int* __restrict__ row_ptr, const int* __restrict__ counts,
    const int* __restrict__ partials, const unsigned int* __restrict__ edges,
    const float* __restrict__ b1, const float* __restrict__ g1,
    const float* __restrict__ beta1, const float* __restrict__ W2,
    __half* __restrict__ h3, int N) {
    __shared__ float lds[4][K_DIM];
    int wave = threadIdx.x >> 6;
    int lane = threadIdx.x & 63;
    int node = blockIdx.x * 4 + wave;
    if (node >= N) return;
    int sub = lane >> 5;   // 0..1
    int ch  = lane & 31;   // halves [4ch, 4ch+4)

    const uint2* rowp = (const uint2*)h1;  // row stride 32 uint2

    float4 acc = make_float4(0.0f, 0.0f, 0.0f, 0.0f);
    if (sub == 0) {
        float dd = dinv[node];
        float w = dd * dd;
        uint2 hv = rowp[(size_t)node * 32 + ch];
        float2 fa = h2f(hv.x), fb = h2f(hv.y);
        acc.x = fa.x * w; acc.y = fa.y * w;
        acc.z = fb.x * w; acc.w = fb.y * w;
    }

    int end = row_ptr[node] + partials[node >> 8];
    int beg = end - counts[node];
    beg = __builtin_amdgcn_readfirstlane(beg);
    end = __builtin_amdgcn_readfirstlane(end);

    for (int e = beg; e < end; e += 16) {
        unsigned int rec[16];
#pragma unroll
        for (int i = 0; i < 16; ++i) rec[i] = edges[e + i];  // uniform -> s_load
        uint2 v[8];
#pragma unroll
        for (int i = 0; i < 8; ++i) {
            unsigned int r = (sub == 0) ? rec[2 * i] : rec[2 * i + 1];
            v[i] = rowp[(size_t)(r & 0xFFFFu) * 32 + ch];
        }
#pragma unroll
        for (int i = 0; i < 8; ++i) {
            unsigned int r = (sub == 0) ? rec[2 * i] : rec[2 * i + 1];
            float w = (e + 2 * i + sub < end) ? wbits(r) : 0.0f;
            float2 fa = h2f(v[i].x), fb = h2f(v[i].y);
            acc.x = fmaf(fa.x, w, acc.x);
            acc.y = fmaf(fa.y, w, acc.y);
            acc.z = fmaf(fb.x, w, acc.z);
            acc.w = fmaf(fb.y, w, acc.w);
        }
    }

    // combine subs: after this, both subs hold the full per-channel sums
    acc.x += __shfl_xor(acc.x, 32);
    acc.y += __shfl_xor(acc.y, 32);
    acc.z += __shfl_xor(acc.z, 32);
    acc.w += __shfl_xor(acc.w, 32);

    // bias + LN + ReLU (channels duplicated 2x -> reductions use 1/256)
    float4 bb = ((const float4*)b1)[ch];
    acc.x += bb.x; acc.y += bb.y; acc.z += bb.z; acc.w += bb.w;
    float s = acc.x + acc.y + acc.z + acc.w;
    for (int off = 32; off; off >>= 1) s += __shfl_xor(s, off);
    float mu = s * (1.0f / 256.0f);
    float d0 = acc.x - mu, d1 = acc.y - mu, d2 = acc.z - mu, d3 = acc.w - mu;
    float q = d0 * d0 + d1 * d1 + d2 * d2 + d3 * d3;
    for (int off = 32; off; off >>= 1) q += __shfl_xor(q, off);
    float rstd = rsqrtf(q * (1.0f / 256.0f) + 1e-5f);
    float4 gg = ((const float4*)g1)[ch];
    float4 be = ((const float4*)beta1)[ch];
    float o0 = fmaxf(fmaf(d0 * rstd, gg.x, be.x), 0.0f);
    float o1 = fmaxf(fmaf(d1 * rstd, gg.y, be.y), 0.0f);
    float o2 = fmaxf(fmaf(d2 * rstd, gg.z, be.z), 0.0f);
    float o3 = fmaxf(fmaf(d3 * rstd, gg.w, be.w), 0.0f);

    if (sub == 0) ((float4*)&lds[wave][0])[ch] = make_float4(o0, o1, o2, o3);

    // 128x64 matvec via LDS broadcast; lane owns output col = lane
    float o = 0.0f;
#pragma unroll 8
    for (int k = 0; k < K_DIM; k += 4) {
        float4 vv = *(const float4*)&lds[wave][k];
        o = fmaf(vv.x, W2[(size_t)(k + 0) * 64 + lane], o);
        o = fmaf(vv.y, W2[(size_t)(k + 1) * 64 + lane], o);
        o = fmaf(vv.z, W2[(size_t)(k + 2) * 64 + lane], o);
        o = fmaf(vv.w, W2[(size_t)(k + 3) * 64 + lane], o);
    }
    h3[(size_t)node * 64 + lane] = __float2half(o);
}

// ---------- gather2 fused: agg(h3) -> +b2 -> LN -> ReLU -> L2 -> out ----------
// Wave = one node. lane = sub(4) x ch(16); uint2 loads; 16 edges/iter.
// Channels duplicated 4x after combines (reductions use /256).
__global__ __launch_bounds__(256) void gather2_fused_kernel(
    const __half* __restrict__ h3, const float* __restrict__ dinv,
    const int* __restrict__ row_ptr, const int* __restrict__ counts,
    const int* __restrict__ partials, const unsigned int* __restrict__ edges,
    const float* __restrict__ b2, const float* __restrict__ g2,
    const float* __restrict__ beta2, float* __restrict__ out, int N) {
    int wave = threadIdx.x >> 6;
    int lane = threadIdx.x & 63;
    int node = blockIdx.x * 4 + wave;
    if (node >= N) return;
    int sub = lane >> 4;   // 0..3
    int ch  = lane & 15;   // halves [4ch, 4ch+4)

    const uint2* rowp = (const uint2*)h3;  // row stride 16 uint2

    float4 acc = make_float4(0.0f, 0.0f, 0.0f, 0.0f);
    if (sub == 0) {
        float dd = dinv[node];
        float w = dd * dd;
        uint2 hv = rowp[(size_t)node * 16 + ch];
        float2 fa = h2f(hv.x), fb = h2f(hv.y);
        acc.x = fa.x * w; acc.y = fa.y * w;
        acc.z = fb.x * w; acc.w = fb.y * w;
    }

    int end = row_ptr[node] + partials[node >> 8];
    int beg = end - counts[node];
    beg = __builtin_amdgcn_readfirstlane(beg);
    end = __builtin_amdgcn_readfirstlane(end);

    for (int e = beg; e < end; e += 16) {
        unsigned int rec[16];
#pragma unroll
        for (int i = 0; i < 16; ++i) rec[i] = edges[e + i];
        uint2 v[4];
#pragma unroll
        for (int i = 0; i < 4; ++i) {
            unsigned int r = (sub == 0) ? rec[4 * i]
                           : (sub == 1) ? rec[4 * i + 1]
                           : (sub == 2) ? rec[4 * i + 2]
                                        : rec[4 * i + 3];
            v[i] = rowp[(size_t)(r & 0xFFFFu) * 16 + ch];
        }
#pragma unroll
        for (int i = 0; i < 4; ++i) {
            unsigned int r = (sub == 0) ? rec[4 * i]
                           : (sub == 1) ? rec[4 * i + 1]
                           : (sub == 2) ? rec[4 * i + 2]
                                        : rec[4 * i + 3];
            float w = (e + 4 * i + sub < end) ? wbits(r) : 0.0f;
            float2 fa = h2f(v[i].x), fb = h2f(v[i].y);
            acc.x = fmaf(fa.x, w, acc.x);
            acc.y = fmaf(fa.y, w, acc.y);
            acc.z = fmaf(fb.x, w, acc.z);
            acc.w = fmaf(fb.y, w, acc.w);
        }
    }

    // combine 4 subs
    acc.x += __shfl_xor(acc.x, 16);
    acc.y += __shfl_xor(acc.y, 16);
    acc.z += __shfl_xor(acc.z, 16);
    acc.w += __shfl_xor(acc.w, 16);
    acc.x += __shfl_xor(acc.x, 32);
    acc.y += __shfl_xor(acc.y, 32);
    acc.z += __shfl_xor(acc.z, 32);
    acc.w += __shfl_xor(acc.w, 32);

    // bias + LN + ReLU + L2 (channels duplicated 4x -> reductions use /256)
    float4 bb = ((const float4*)b2)[ch];
    acc.x += bb.x; acc.y += bb.y; acc.z += bb.z; acc.w += bb.w;
    float s = acc.x + acc.y + acc.z + acc.w;
    for (int off = 32; off; off >>= 1) s += __shfl_xor(s, off);
    float mu = s * (1.0f / 256.0f);
    float d0 = acc.x - mu, d1 = acc.y - mu, d2 = acc.z - mu, d3 = acc.w - mu;
    float q = d0 * d0 + d1 * d1 + d2 * d2 + d3 * d3;
    for (int off = 32; off; off >>= 1) q += __shfl_xor(q, off);
    float rstd = rsqrtf(q * (1.0f / 256.0f) + 1e-5f);
    float4 gg = ((const float4*)g2)[ch];
    float4 be = ((const float4*)beta2)[ch];
    float o0 = fmaxf(fmaf(d0 * rstd, gg.x, be.x), 0.0f);
    float o1 = fmaxf(fmaf(d1 * rstd, gg.y, be.y), 0.0f);
    float o2 = fmaxf(fmaf(d2 * rstd, gg.z, be.z), 0.0f);
    float o3 = fmaxf(fmaf(d3 * rstd, gg.w, be.w), 0.0f);

    float q2 = o0 * o0 + o1 * o1 + o2 * o2 + o3 * o3;
    for (int off = 32; off; off >>= 1) q2 += __shfl_xor(q2, off);
    float nrm = sqrtf(q2) * 0.5f;  // 4x duplication
    float inv = 1.0f / fmaxf(nrm, 1e-12f);

    if (sub == 0)
        ((float4*)(out + (size_t)node * 64))[ch] =
            make_float4(o0 * inv, o1 * inv, o2 * inv, o3 * inv);
}

extern "C" void kernel_launch(void* const* d_in, const int* in_sizes, int n_in,
                              void* d_out, int out_size, void* d_ws, size_t ws_size,
                              hipStream_t stream) {
    const float* x     = (const float*)d_in[0];
    const int*   ei    = (const int*)d_in[1];
    const float* W1    = (const float*)d_in[2];
    const float* b1    = (const float*)d_in[3];
    const float* g1    = (const float*)d_in[4];
    const float* beta1 = (const float*)d_in[5];
    const float* W2    = (const float*)d_in[6];
    const float* b2    = (const float*)d_in[7];
    const float* g2    = (const float*)d_in[8];
    const float* beta2 = (const float*)d_in[9];

    const int N = in_sizes[0] / 128;
    const int E = in_sizes[1] / 2;
    const int* src = ei;       // edge_index[0]
    const int* dst = ei + E;   // edge_index[1]
    float* out = (float*)d_out;

    // Workspace (~23 MB)
    char* p = (char*)d_ws;
    auto alloc = [&](size_t bytes) { char* r = p; p += (bytes + 255) & ~(size_t)255; return r; };
    int*          counts   = (int*)alloc((size_t)N * 4);
    int*          row_ptr  = (int*)alloc((size_t)N * 4);
    int*          partials = (int*)alloc(256 * 4);
    float*        dinv     = (float*)alloc((size_t)N * 4);
    unsigned int* edges    = (unsigned int*)alloc(((size_t)E + 64) * 4);  // +pad
    _Float16*     WT       = (_Float16*)alloc(128 * 128 * 2);
    __half*       h1       = (__half*)alloc((size_t)N * 128 * 2);
    __half*       h3       = (__half*)alloc((size_t)N * 64 * 2);

    const int nb_nodes = (N + 255) / 256;
    const int nb_edges = (E + 255) / 256;
    const int nb_wave_nodes = (N + 3) / 4;

    // CSR build + dinv + packed 4-byte edge records (+ zeroed pad)
    hipMemsetAsync(counts, 0, (size_t)N * 4, stream);
    hipMemsetAsync(edges + E, 0, 64 * 4, stream);
    hist_kernel<<<nb_edges, 256, 0, stream>>>(dst, counts, E);
    scan_block_kernel<<<nb_nodes, 256, 0, stream>>>(counts, row_ptr, partials, dinv, N);
    scan_partials_kernel<<<1, 256, 0, stream>>>(partials, nb_nodes);
    fill_kernel<<<nb_edges, 256, 0, stream>>>(src, dst, dinv, row_ptr, partials, edges, E);

    // layer 1 GEMM (MFMA, f16 out)
    wt_prep_kernel<<<64, 256, 0, stream>>>(W1, WT);
    gemm1_mfma_kernel<<<(N + 63) / 64, 256, 0, stream>>>(x, WT, h1, N);

    // layer 1 aggregate + LN + ReLU + layer 2 GEMM (fused)
    gather1_fused_kernel<<<nb_wave_nodes, 256, 0, stream>>>(
        h1, dinv, row_ptr, counts, partials, edges, b1, g1, beta1, W2, h3, N);

    // layer 2 aggregate + LN + ReLU + L2 (fused)
    gather2_fused_kernel<<<nb_wave_nodes, 256, 0, stream>>>(
        h3, dinv, row_ptr, counts, partials, edges, b2, g2, beta2, out, N);
}